// Round 9
// baseline (24.724 us; speedup 1.0000x reference)
//
#include <hip/hip_runtime.h>
#include <math.h>

#define NB 16
#define KB 32
#define KA 16
#define G  64
#define GP1 (G + 1)
#define ITERS 4

typedef float f4v __attribute__((ext_vector_type(4)));
typedef int   i4v __attribute__((ext_vector_type(4)));
typedef float f2v __attribute__((ext_vector_type(2)));

__device__ __forceinline__ float softplus_f(float v) {
    // numerically stable log(1 + exp(v))
    return fmaxf(v, 0.0f) + log1pf(expf(-fabsf(v)));
}

// Round-8 fused kernel + a SECOND full evaluation pass (identical output,
// deterministic) behind a compiler barrier. Purpose: pass 2 runs cache-hot,
// so dur - dur_round8 isolates the streaming loop's non-HBM cost.
__global__ __launch_bounds__(256) void BucketAdjustedHinge_kernel(
    const float* __restrict__ x,
    const float* __restrict__ x_mins,
    const float* __restrict__ x_maxs,
    const float* __restrict__ clip_los,
    const float* __restrict__ clip_his,
    const float* __restrict__ base_knots,
    const float* __restrict__ base_raw_w,
    const float* __restrict__ base_bias,
    const float* __restrict__ adj_knots,
    const float* __restrict__ adj_raw_w,
    const float* __restrict__ adj_bias,
    const int*   __restrict__ bucket_idx,
    float*       __restrict__ out,
    int n)
{
    __shared__ float  s_bw[KB], s_bk[KB], s_ak[KA];
    __shared__ float  s_aw[NB][KA + 1];     // +1 pad: pass-1 lanes differ in b
    __shared__ float4 s_abc[NB];            // {a, c, Lb, Hb}
    __shared__ float  s_bias[NB];
    __shared__ float  s_x0[NB], s_x1[NB];
    __shared__ float  s_fv[GP1][NB + 1];    // gridpoint values, +1 pad
    __shared__ f2v    s_lut[NB * G];        // dense: idx = (b<<6)|cell

    const int tid = threadIdx.x;
    const int gsz = gridDim.x * blockDim.x;
    const int t   = blockIdx.x * blockDim.x + tid;
    const int n4  = n >> 2;

    const f4v* __restrict__ x4v = (const f4v*)x;
    const i4v* __restrict__ b4v = (const i4v*)bucket_idx;
    f4v*       __restrict__ o4v = (f4v*)out;

    // ---- issue ALL stream loads first; their latency hides the LUT build ----
    f4v xa[ITERS]; i4v ba[ITERS];
    #pragma unroll
    for (int k = 0; k < ITERS; ++k) {
        const int idx = t + k * gsz;
        if (idx < n4) { xa[k] = x4v[idx]; ba[k] = b4v[idx]; }
    }

    // ---- stage params (small loads; queue behind the stream loads) ----
    if (tid < NB * KA) s_aw[tid >> 4][tid & (KA - 1)] = softplus_f(adj_raw_w[tid]);
    if (tid < KB) { s_bw[tid] = softplus_f(base_raw_w[tid]); s_bk[tid] = base_knots[tid]; }
    if (tid < KA) s_ak[tid] = adj_knots[tid];
    if (tid < NB) {
        const float mn = x_mins[tid], mx = x_maxs[tid];
        const float inva = mx - mn + 1e-12f;
        const float a = 1.0f / inva;
        const float c = -mn * a;
        const float lo = clip_los[tid], hi = clip_his[tid];
        // fold clip bounds through monotone affine + [0,1] clamp;
        // non-finite bound => no clipping on that side
        const float Lb = isfinite(lo) ? fminf(fmaxf(fmaf(lo, a, c), 0.0f), 1.0f) : 0.0f;
        const float Hb = isfinite(hi) ? fmaxf(fminf(fmaf(hi, a, c), 1.0f), 0.0f) : 1.0f;
        s_abc[tid] = make_float4(a, c, Lb, Hb);
        s_bias[tid] = adj_bias[tid] + base_bias[0];
        // active x-range of bucket (F_b exactly constant outside)
        const float x0 = fmaf(Lb, inva, mn);
        const float x1 = fmaf(Hb, inva, mn);
        s_x0[tid] = fminf(x0, x1);
        s_x1[tid] = fmaxf(x0, x1);
    }
    __syncthreads();

    // ---- global x-range (identical in every block; broadcast LDS reads) ----
    float xlo = s_x0[0], xhi = s_x1[0];
    #pragma unroll
    for (int i = 1; i < NB; ++i) { xlo = fminf(xlo, s_x0[i]); xhi = fmaxf(xhi, s_x1[i]); }
    if (!(xhi > xlo)) xhi = xlo + 1.0f;            // degenerate guard
    const float ginv  = (float)G / (xhi - xlo);    // 1/hstep
    const float hstep = (xhi - xlo) * (1.0f / (float)G);
    const float xlg   = xlo * ginv;

    // ---- pass 1: exact F_b at gridpoints; lanes: b = i&15 (conflict-free) ----
    for (int i = tid; i < NB * GP1; i += 256) {
        const int j = i >> 4, b = i & (NB - 1);
        const float xj = fmaf(hstep, (float)j, xlo);
        const float4 p = s_abc[b];
        const float v = fminf(fmaxf(fmaf(xj, p.x, p.y), p.z), p.w);
        float f = s_bias[b];
        #pragma unroll 8
        for (int k = 0; k < KB; ++k)
            f = fmaf(s_bw[k], fminf(v, s_bk[k]), f);
        #pragma unroll 8
        for (int k = 0; k < KA; ++k)
            f = fmaf(s_aw[b][k], fminf(v, s_ak[k]), f);
        s_fv[j][b] = f;
    }
    __syncthreads();

    // ---- pass 2: cell coefficients; i == (b<<6)|j so writes are linear ----
    for (int i = tid; i < NB * G; i += 256) {
        const int b = i >> 6, j = i & (G - 1);
        const float fl = s_fv[j][b], fr = s_fv[j + 1][b];
        const float c1 = (fr - fl) * ginv;
        const float xj = fmaf(hstep, (float)j, xlo);
        const float c0 = fmaf(-c1, xj, fl);
        s_lut[i] = (f2v){c0, c1};
    }
    __syncthreads();

    // ---- streaming evaluation (pass A: identical to round 8) ----
    #define EVAL1(xr, b, dstf)                                             \
        {                                                                  \
            const float xc = fminf(fmaxf((xr), xlo), xhi);                 \
            const float tt = fmaf(xc, ginv, -xlg);                         \
            const int cell = min((int)tt, G - 1);                          \
            const f2v cf = s_lut[((b) << 6) | cell];                       \
            (dstf) = fmaf(xc, cf.y, cf.x);                                 \
        }

    #pragma unroll
    for (int k = 0; k < ITERS; ++k) {
        const int idx = t + k * gsz;
        if (idx < n4) {
            f4v r;
            EVAL1(xa[k].x, ba[k].x, r.x); EVAL1(xa[k].y, ba[k].y, r.y);
            EVAL1(xa[k].z, ba[k].z, r.z); EVAL1(xa[k].w, ba[k].w, r.w);
            o4v[idx] = r;
        }
    }
    for (int idx = t + ITERS * gsz; idx < n4; idx += gsz) {
        const f4v xv = x4v[idx];
        const i4v bv = b4v[idx];
        f4v r;
        EVAL1(xv.x, bv.x, r.x); EVAL1(xv.y, bv.y, r.y);
        EVAL1(xv.z, bv.z, r.z); EVAL1(xv.w, bv.w, r.w);
        o4v[idx] = r;
    }
    for (int i = (n4 << 2) + t; i < n; i += gsz) {
        float r;
        EVAL1(x[i], bucket_idx[i], r);
        out[i] = r;
    }

    // ---- CALIBRATION pass B: full re-load + re-eval + re-store of identical
    // values, cache-hot. Compiler barrier stops CSE/merging with pass A. ----
    asm volatile("" ::: "memory");
    for (int idx = t; idx < n4; idx += gsz) {
        const f4v xv = x4v[idx];
        const i4v bv = b4v[idx];
        f4v r;
        EVAL1(xv.x, bv.x, r.x); EVAL1(xv.y, bv.y, r.y);
        EVAL1(xv.z, bv.z, r.z); EVAL1(xv.w, bv.w, r.w);
        o4v[idx] = r;
    }
    for (int i = (n4 << 2) + t; i < n; i += gsz) {
        float r;
        EVAL1(x[i], bucket_idx[i], r);
        out[i] = r;
    }
    #undef EVAL1
}

extern "C" void kernel_launch(void* const* d_in, const int* in_sizes, int n_in,
                              void* d_out, int out_size, void* d_ws, size_t ws_size,
                              hipStream_t stream) {
    const float* x          = (const float*)d_in[0];
    const float* x_mins     = (const float*)d_in[1];
    const float* x_maxs     = (const float*)d_in[2];
    const float* clip_los   = (const float*)d_in[3];
    const float* clip_his   = (const float*)d_in[4];
    const float* base_knots = (const float*)d_in[5];
    const float* base_raw_w = (const float*)d_in[6];
    const float* base_bias  = (const float*)d_in[7];
    const float* adj_knots  = (const float*)d_in[8];
    const float* adj_raw_w  = (const float*)d_in[9];
    const float* adj_bias   = (const float*)d_in[10];
    const int*   bucket_idx = (const int*)d_in[11];
    float* out = (float*)d_out;

    const int n = in_sizes[0];
    // 1024 blocks x 256 thr x ITERS=4 float4-iters == n/4 exactly at N=4M
    const int blocks = 1024;
    BucketAdjustedHinge_kernel<<<blocks, 256, 0, stream>>>(
        x, x_mins, x_maxs, clip_los, clip_his,
        base_knots, base_raw_w, base_bias,
        adj_knots, adj_raw_w, adj_bias,
        bucket_idx, out, n);
}

// Round 10
// 16.507 us; speedup vs baseline: 1.4978x; 1.4978x over previous
//
#include <hip/hip_runtime.h>
#include <math.h>

#define NB 16
#define KB 32
#define KA 16
#define G  64
#define GP1 (G + 1)
#define ITERS 4

typedef float f4v __attribute__((ext_vector_type(4)));
typedef int   i4v __attribute__((ext_vector_type(4)));
typedef float f2v __attribute__((ext_vector_type(2)));

__device__ __forceinline__ float softplus_f(float v) {
    // numerically stable log(1 + exp(v))
    return fmaxf(v, 0.0f) + log1pf(expf(-fabsf(v)));
}

// Fused kernel (round-8 structure): every block builds the 16x64-cell PWL
// table for F_b(x) = f_b(clamp(affine_b(x))) in LDS, then streams 16
// elements/thread through it. Stores are NONTEMPORAL: out is never re-read,
// and avoiding L2/L3 allocation prevents eviction of (a) dirty poison lines
// from the 268 MB ws fill (writeback amplification seen in round 2's
// WRITE_SIZE=67MB for a 16MB output) and (b) the input streams' L3 residency
// across graph replays.
__global__ __launch_bounds__(256) void BucketAdjustedHinge_kernel(
    const float* __restrict__ x,
    const float* __restrict__ x_mins,
    const float* __restrict__ x_maxs,
    const float* __restrict__ clip_los,
    const float* __restrict__ clip_his,
    const float* __restrict__ base_knots,
    const float* __restrict__ base_raw_w,
    const float* __restrict__ base_bias,
    const float* __restrict__ adj_knots,
    const float* __restrict__ adj_raw_w,
    const float* __restrict__ adj_bias,
    const int*   __restrict__ bucket_idx,
    float*       __restrict__ out,
    int n)
{
    __shared__ float  s_bw[KB], s_bk[KB], s_ak[KA];
    __shared__ float  s_aw[NB][KA + 1];     // +1 pad: pass-1 lanes differ in b
    __shared__ float4 s_abc[NB];            // {a, c, Lb, Hb}
    __shared__ float  s_bias[NB];
    __shared__ float  s_x0[NB], s_x1[NB];
    __shared__ float  s_fv[GP1][NB + 1];    // gridpoint values, +1 pad
    __shared__ f2v    s_lut[NB * G];        // dense: idx = (b<<6)|cell

    const int tid = threadIdx.x;
    const int gsz = gridDim.x * blockDim.x;
    const int t   = blockIdx.x * blockDim.x + tid;
    const int n4  = n >> 2;

    const f4v* __restrict__ x4v = (const f4v*)x;
    const i4v* __restrict__ b4v = (const i4v*)bucket_idx;
    f4v*       __restrict__ o4v = (f4v*)out;

    // ---- issue ALL stream loads first; their latency hides the LUT build ----
    f4v xa[ITERS]; i4v ba[ITERS];
    #pragma unroll
    for (int k = 0; k < ITERS; ++k) {
        const int idx = t + k * gsz;
        if (idx < n4) { xa[k] = x4v[idx]; ba[k] = b4v[idx]; }
    }

    // ---- stage params (small loads; queue behind the stream loads) ----
    if (tid < NB * KA) s_aw[tid >> 4][tid & (KA - 1)] = softplus_f(adj_raw_w[tid]);
    if (tid < KB) { s_bw[tid] = softplus_f(base_raw_w[tid]); s_bk[tid] = base_knots[tid]; }
    if (tid < KA) s_ak[tid] = adj_knots[tid];
    if (tid < NB) {
        const float mn = x_mins[tid], mx = x_maxs[tid];
        const float inva = mx - mn + 1e-12f;
        const float a = 1.0f / inva;
        const float c = -mn * a;
        const float lo = clip_los[tid], hi = clip_his[tid];
        // fold clip bounds through monotone affine + [0,1] clamp;
        // non-finite bound => no clipping on that side
        const float Lb = isfinite(lo) ? fminf(fmaxf(fmaf(lo, a, c), 0.0f), 1.0f) : 0.0f;
        const float Hb = isfinite(hi) ? fmaxf(fminf(fmaf(hi, a, c), 1.0f), 0.0f) : 1.0f;
        s_abc[tid] = make_float4(a, c, Lb, Hb);
        s_bias[tid] = adj_bias[tid] + base_bias[0];
        // active x-range of bucket (F_b exactly constant outside)
        const float x0 = fmaf(Lb, inva, mn);
        const float x1 = fmaf(Hb, inva, mn);
        s_x0[tid] = fminf(x0, x1);
        s_x1[tid] = fmaxf(x0, x1);
    }
    __syncthreads();

    // ---- global x-range (identical in every block; broadcast LDS reads) ----
    float xlo = s_x0[0], xhi = s_x1[0];
    #pragma unroll
    for (int i = 1; i < NB; ++i) { xlo = fminf(xlo, s_x0[i]); xhi = fmaxf(xhi, s_x1[i]); }
    if (!(xhi > xlo)) xhi = xlo + 1.0f;            // degenerate guard
    const float ginv  = (float)G / (xhi - xlo);    // 1/hstep
    const float hstep = (xhi - xlo) * (1.0f / (float)G);
    const float xlg   = xlo * ginv;

    // ---- pass 1: exact F_b at gridpoints; lanes: b = i&15 (conflict-free) ----
    for (int i = tid; i < NB * GP1; i += 256) {
        const int j = i >> 4, b = i & (NB - 1);
        const float xj = fmaf(hstep, (float)j, xlo);
        const float4 p = s_abc[b];
        const float v = fminf(fmaxf(fmaf(xj, p.x, p.y), p.z), p.w);
        float f = s_bias[b];
        #pragma unroll 8
        for (int k = 0; k < KB; ++k)
            f = fmaf(s_bw[k], fminf(v, s_bk[k]), f);
        #pragma unroll 8
        for (int k = 0; k < KA; ++k)
            f = fmaf(s_aw[b][k], fminf(v, s_ak[k]), f);
        s_fv[j][b] = f;
    }
    __syncthreads();

    // ---- pass 2: cell coefficients; i == (b<<6)|j so writes are linear ----
    for (int i = tid; i < NB * G; i += 256) {
        const int b = i >> 6, j = i & (G - 1);
        const float fl = s_fv[j][b], fr = s_fv[j + 1][b];
        const float c1 = (fr - fl) * ginv;
        const float xj = fmaf(hstep, (float)j, xlo);
        const float c0 = fmaf(-c1, xj, fl);
        s_lut[i] = (f2v){c0, c1};
    }
    __syncthreads();

    // ---- streaming evaluation; NONTEMPORAL stores ----
    #define EVAL1(xr, b, dstf)                                             \
        {                                                                  \
            const float xc = fminf(fmaxf((xr), xlo), xhi);                 \
            const float tt = fmaf(xc, ginv, -xlg);                         \
            const int cell = min((int)tt, G - 1);                          \
            const f2v cf = s_lut[((b) << 6) | cell];                       \
            (dstf) = fmaf(xc, cf.y, cf.x);                                 \
        }

    #pragma unroll
    for (int k = 0; k < ITERS; ++k) {
        const int idx = t + k * gsz;
        if (idx < n4) {
            f4v r;
            EVAL1(xa[k].x, ba[k].x, r.x); EVAL1(xa[k].y, ba[k].y, r.y);
            EVAL1(xa[k].z, ba[k].z, r.z); EVAL1(xa[k].w, ba[k].w, r.w);
            __builtin_nontemporal_store(r, o4v + idx);
        }
    }

    // safety tails (unused at N=4M: grid*ITERS covers n4 exactly, n%4==0)
    for (int idx = t + ITERS * gsz; idx < n4; idx += gsz) {
        const f4v xv = x4v[idx];
        const i4v bv = b4v[idx];
        f4v r;
        EVAL1(xv.x, bv.x, r.x); EVAL1(xv.y, bv.y, r.y);
        EVAL1(xv.z, bv.z, r.z); EVAL1(xv.w, bv.w, r.w);
        __builtin_nontemporal_store(r, o4v + idx);
    }
    for (int i = (n4 << 2) + t; i < n; i += gsz) {
        float r;
        EVAL1(x[i], bucket_idx[i], r);
        __builtin_nontemporal_store(r, out + i);
    }
    #undef EVAL1
}

extern "C" void kernel_launch(void* const* d_in, const int* in_sizes, int n_in,
                              void* d_out, int out_size, void* d_ws, size_t ws_size,
                              hipStream_t stream) {
    const float* x          = (const float*)d_in[0];
    const float* x_mins     = (const float*)d_in[1];
    const float* x_maxs     = (const float*)d_in[2];
    const float* clip_los   = (const float*)d_in[3];
    const float* clip_his   = (const float*)d_in[4];
    const float* base_knots = (const float*)d_in[5];
    const float* base_raw_w = (const float*)d_in[6];
    const float* base_bias  = (const float*)d_in[7];
    const float* adj_knots  = (const float*)d_in[8];
    const float* adj_raw_w  = (const float*)d_in[9];
    const float* adj_bias   = (const float*)d_in[10];
    const int*   bucket_idx = (const int*)d_in[11];
    float* out = (float*)d_out;

    const int n = in_sizes[0];
    // 1024 blocks x 256 thr x ITERS=4 float4-iters == n/4 exactly at N=4M
    const int blocks = 1024;
    BucketAdjustedHinge_kernel<<<blocks, 256, 0, stream>>>(
        x, x_mins, x_maxs, clip_los, clip_his,
        base_knots, base_raw_w, base_bias,
        adj_knots, adj_raw_w, adj_bias,
        bucket_idx, out, n);
}

// Round 11
// 15.491 us; speedup vs baseline: 1.5960x; 1.0656x over previous
//
#include <hip/hip_runtime.h>
#include <math.h>

#define NB 16
#define KB 32
#define KA 16
#define G  64
#define GP1 (G + 1)
#define ITERS 4
#define NTHR 512

typedef float f4v __attribute__((ext_vector_type(4)));
typedef int   i4v __attribute__((ext_vector_type(4)));
typedef float f2v __attribute__((ext_vector_type(2)));

__device__ __forceinline__ float softplus_f(float v) {
    // numerically stable log(1 + exp(v))
    return fmaxf(v, 0.0f) + log1pf(expf(-fabsf(v)));
}

// Fused kernel. Build-phase redesign vs round 8/10: the 80 wave-uniform hinge
// constants {base_knots, softplus(base_raw_w), adj_knots} are staged once in
// LDS, then copied per-thread into REGISTERS (20x ds_read_b128) and the hinge
// loops are fully unrolled on register operands. This removes the ~1560
// wave-level LDS broadcast reads/block (96 per gridpoint) that serialized on
// the shared LDS pipe (~15us/CU at 4 blocks/CU) -- the measured build cost.
// Only s_aw[b][k] (per-lane bucket) remains an LDS gather in pass 1.
// 512x512 grid halves builds/CU; stores stay nontemporal (round-10 win).
__global__ __launch_bounds__(NTHR) void BucketAdjustedHinge_kernel(
    const float* __restrict__ x,
    const float* __restrict__ x_mins,
    const float* __restrict__ x_maxs,
    const float* __restrict__ clip_los,
    const float* __restrict__ clip_his,
    const float* __restrict__ base_knots,
    const float* __restrict__ base_raw_w,
    const float* __restrict__ base_bias,
    const float* __restrict__ adj_knots,
    const float* __restrict__ adj_raw_w,
    const float* __restrict__ adj_bias,
    const int*   __restrict__ bucket_idx,
    float*       __restrict__ out,
    int n)
{
    __shared__ float  s_cst[80];            // [0..31]=bk  [32..63]=softplus(bw)  [64..79]=ak
    __shared__ float  s_aw[NB][KA + 1];     // softplus'd adj weights, +1 pad
    __shared__ float4 s_abc[NB];            // {a, c, Lb, Hb}
    __shared__ float  s_bias[NB];
    __shared__ float  s_x0[NB], s_x1[NB];
    __shared__ float  s_fv[GP1][NB + 1];    // gridpoint values, +1 pad
    __shared__ f2v    s_lut[NB * G];        // dense: idx = (b<<6)|cell

    const int tid = threadIdx.x;
    const int gsz = gridDim.x * blockDim.x;
    const int t   = blockIdx.x * blockDim.x + tid;
    const int n4  = n >> 2;

    const f4v* __restrict__ x4v = (const f4v*)x;
    const i4v* __restrict__ b4v = (const i4v*)bucket_idx;
    f4v*       __restrict__ o4v = (f4v*)out;

    // ---- issue ALL stream loads first; latency hides the LUT build ----
    f4v xa[ITERS]; i4v ba[ITERS];
    #pragma unroll
    for (int k = 0; k < ITERS; ++k) {
        const int idx = t + k * gsz;
        if (idx < n4) { xa[k] = x4v[idx]; ba[k] = b4v[idx]; }
    }

    // ---- stage params into LDS (tiny; queues behind stream loads) ----
    if (tid < KB) { s_cst[tid] = base_knots[tid]; s_cst[KB + tid] = softplus_f(base_raw_w[tid]); }
    if (tid < KA) s_cst[2 * KB + tid] = adj_knots[tid];
    if (tid < NB * KA) s_aw[tid >> 4][tid & (KA - 1)] = softplus_f(adj_raw_w[tid]);
    if (tid < NB) {
        const float mn = x_mins[tid], mx = x_maxs[tid];
        const float inva = mx - mn + 1e-12f;
        const float a = 1.0f / inva;
        const float c = -mn * a;
        const float lo = clip_los[tid], hi = clip_his[tid];
        // fold clip bounds through monotone affine + [0,1] clamp;
        // non-finite bound => no clipping on that side
        const float Lb = isfinite(lo) ? fminf(fmaxf(fmaf(lo, a, c), 0.0f), 1.0f) : 0.0f;
        const float Hb = isfinite(hi) ? fmaxf(fminf(fmaf(hi, a, c), 1.0f), 0.0f) : 1.0f;
        s_abc[tid] = make_float4(a, c, Lb, Hb);
        s_bias[tid] = adj_bias[tid] + base_bias[0];
        // active x-range of bucket (F_b exactly constant outside)
        const float x0 = fmaf(Lb, inva, mn);
        const float x1 = fmaf(Hb, inva, mn);
        s_x0[tid] = fminf(x0, x1);
        s_x1[tid] = fmaxf(x0, x1);
    }
    __syncthreads();

    // ---- global x-range (broadcast LDS reads; identical all blocks) ----
    float xlo = s_x0[0], xhi = s_x1[0];
    #pragma unroll
    for (int i = 1; i < NB; ++i) { xlo = fminf(xlo, s_x0[i]); xhi = fmaxf(xhi, s_x1[i]); }
    if (!(xhi > xlo)) xhi = xlo + 1.0f;            // degenerate guard
    const float ginv  = (float)G / (xhi - xlo);    // 1/hstep
    const float hstep = (xhi - xlo) * (1.0f / (float)G);
    const float xlg   = xlo * ginv;

    // ---- copy uniform constants to registers (20x ds_read_b128) ----
    float c_bk[KB], c_bw[KB], c_ak[KA];
    {
        const f4v* cst4 = (const f4v*)s_cst;
        #pragma unroll
        for (int q = 0; q < KB / 4; ++q) {
            const f4v v0 = cst4[q];
            const f4v v1 = cst4[KB / 4 + q];
            c_bk[4 * q] = v0.x; c_bk[4 * q + 1] = v0.y; c_bk[4 * q + 2] = v0.z; c_bk[4 * q + 3] = v0.w;
            c_bw[4 * q] = v1.x; c_bw[4 * q + 1] = v1.y; c_bw[4 * q + 2] = v1.z; c_bw[4 * q + 3] = v1.w;
        }
        #pragma unroll
        for (int q = 0; q < KA / 4; ++q) {
            const f4v v2 = cst4[2 * KB / 4 + q];
            c_ak[4 * q] = v2.x; c_ak[4 * q + 1] = v2.y; c_ak[4 * q + 2] = v2.z; c_ak[4 * q + 3] = v2.w;
        }
    }

    // ---- pass 1: exact F_b at gridpoints; register-operand hinge loops ----
    // i = j*16 + b: lanes span b (4-lane broadcast on s_aw), conflict-free
    for (int i = tid; i < NB * GP1; i += NTHR) {
        const int j = i >> 4, b = i & (NB - 1);
        const float xj = fmaf(hstep, (float)j, xlo);
        const float4 p = s_abc[b];
        const float v = fminf(fmaxf(fmaf(xj, p.x, p.y), p.z), p.w);
        float f0 = s_bias[b], f1 = 0.0f;
        #pragma unroll
        for (int k = 0; k < KB; k += 2) {
            f0 = fmaf(c_bw[k],     fminf(v, c_bk[k]),     f0);
            f1 = fmaf(c_bw[k + 1], fminf(v, c_bk[k + 1]), f1);
        }
        #pragma unroll
        for (int k = 0; k < KA; k += 2) {
            f0 = fmaf(s_aw[b][k],     fminf(v, c_ak[k]),     f0);
            f1 = fmaf(s_aw[b][k + 1], fminf(v, c_ak[k + 1]), f1);
        }
        s_fv[j][b] = f0 + f1;
    }
    __syncthreads();

    // ---- pass 2: cell coefficients; i == (b<<6)|j so writes are linear ----
    for (int i = tid; i < NB * G; i += NTHR) {
        const int b = i >> 6, j = i & (G - 1);
        const float fl = s_fv[j][b], fr = s_fv[j + 1][b];
        const float c1 = (fr - fl) * ginv;
        const float xj = fmaf(hstep, (float)j, xlo);
        const float c0 = fmaf(-c1, xj, fl);
        s_lut[i] = (f2v){c0, c1};
    }
    __syncthreads();

    // ---- streaming evaluation; NONTEMPORAL stores ----
    #define EVAL1(xr, b, dstf)                                             \
        {                                                                  \
            const float xc = fminf(fmaxf((xr), xlo), xhi);                 \
            const float tt = fmaf(xc, ginv, -xlg);                         \
            const int cell = min((int)tt, G - 1);                          \
            const f2v cf = s_lut[((b) << 6) | cell];                       \
            (dstf) = fmaf(xc, cf.y, cf.x);                                 \
        }

    #pragma unroll
    for (int k = 0; k < ITERS; ++k) {
        const int idx = t + k * gsz;
        if (idx < n4) {
            f4v r;
            EVAL1(xa[k].x, ba[k].x, r.x); EVAL1(xa[k].y, ba[k].y, r.y);
            EVAL1(xa[k].z, ba[k].z, r.z); EVAL1(xa[k].w, ba[k].w, r.w);
            __builtin_nontemporal_store(r, o4v + idx);
        }
    }

    // safety tails (unused at N=4M: grid*ITERS covers n4 exactly, n%4==0)
    for (int idx = t + ITERS * gsz; idx < n4; idx += gsz) {
        const f4v xv = x4v[idx];
        const i4v bv = b4v[idx];
        f4v r;
        EVAL1(xv.x, bv.x, r.x); EVAL1(xv.y, bv.y, r.y);
        EVAL1(xv.z, bv.z, r.z); EVAL1(xv.w, bv.w, r.w);
        __builtin_nontemporal_store(r, o4v + idx);
    }
    for (int i = (n4 << 2) + t; i < n; i += gsz) {
        float r;
        EVAL1(x[i], bucket_idx[i], r);
        __builtin_nontemporal_store(r, out + i);
    }
    #undef EVAL1
}

extern "C" void kernel_launch(void* const* d_in, const int* in_sizes, int n_in,
                              void* d_out, int out_size, void* d_ws, size_t ws_size,
                              hipStream_t stream) {
    const float* x          = (const float*)d_in[0];
    const float* x_mins     = (const float*)d_in[1];
    const float* x_maxs     = (const float*)d_in[2];
    const float* clip_los   = (const float*)d_in[3];
    const float* clip_his   = (const float*)d_in[4];
    const float* base_knots = (const float*)d_in[5];
    const float* base_raw_w = (const float*)d_in[6];
    const float* base_bias  = (const float*)d_in[7];
    const float* adj_knots  = (const float*)d_in[8];
    const float* adj_raw_w  = (const float*)d_in[9];
    const float* adj_bias   = (const float*)d_in[10];
    const int*   bucket_idx = (const int*)d_in[11];
    float* out = (float*)d_out;

    const int n = in_sizes[0];
    // 512 blocks x 512 thr x ITERS=4 float4-iters == n/4 exactly at N=4M;
    // <=2 blocks/CU halves redundant LUT builds per CU vs round 8.
    const int blocks = 512;
    BucketAdjustedHinge_kernel<<<blocks, NTHR, 0, stream>>>(
        x, x_mins, x_maxs, clip_los, clip_his,
        base_knots, base_raw_w, base_bias,
        adj_knots, adj_raw_w, adj_bias,
        bucket_idx, out, n);
}